// Round 6
// baseline (387.073 us; speedup 1.0000x reference)
//
#include <hip/hip_runtime.h>
#include <hip/hip_bf16.h>
#include <hip/hip_fp16.h>
#include <math.h>

// AdaptGNN: B=8, N=2048, D=H=128, 3 layers.
// R6: agg at 2 blocks/CU (512 blocks, P-tile 32, 256 thr) so barriers/latency
// overlap across blocks; ew converted to fp16 once (67 MB -> L3-resident
// across all 3 layers; fp32 134 MB was thrashing L3: FETCH=101MB/layer).

typedef __attribute__((ext_vector_type(8))) short bf16x8;
typedef __attribute__((ext_vector_type(4))) short bf16x4;
typedef __attribute__((ext_vector_type(4))) float f32x4;

static constexpr int kB = 8, kN = 2048, kH = 128;

static __device__ __forceinline__ ushort bf16bits(float f) {
    __hip_bfloat16 hb = __float2bfloat16(f);
    return *reinterpret_cast<ushort*>(&hb);
}
static __device__ __forceinline__ ushort f16bits(float f) {
    __half h = __float2half(f);
    return *reinterpret_cast<ushort*>(&h);
}
static __device__ __forceinline__ float f16val(ushort u) {
    __half h = *reinterpret_cast<__half*>(&u);
    return __half2float(h);
}

// ---------------- x -> bf16 ----------------
__global__ __launch_bounds__(256) void cvt_bf16_kernel(
    const float* __restrict__ src, ushort* __restrict__ dst, int n4)
{
    int i = blockIdx.x * 256 + threadIdx.x;
    if (i >= n4) return;
    float4 v = ((const float4*)src)[i];
    bf16x4 o;
    o[0] = (short)bf16bits(v.x); o[1] = (short)bf16bits(v.y);
    o[2] = (short)bf16bits(v.z); o[3] = (short)bf16bits(v.w);
    ((bf16x4*)dst)[i] = o;
}

// ---------------- ew (fp32) -> fp16, streamed once ----------------
__global__ __launch_bounds__(256) void cvt_ew_kernel(
    const float* __restrict__ ew, ushort* __restrict__ ew16)
{
    int i = blockIdx.x * 256 + threadIdx.x;   // x4 elements, 33.55M total
    float4 v = ((const float4*)ew)[i];
    bf16x4 o;  // 4 ushorts
    o[0] = (short)f16bits(v.x); o[1] = (short)f16bits(v.y);
    o[2] = (short)f16bits(v.z); o[3] = (short)f16bits(v.w);
    ((bf16x4*)ew16)[i] = o;
}

// WT[l][c][d] = bf16(W_l[d][c])
__global__ __launch_bounds__(256) void cvt_wT_kernel(
    const float* __restrict__ W0, const float* __restrict__ W1,
    const float* __restrict__ W2, ushort* __restrict__ WT)
{
    const float* W = blockIdx.y == 0 ? W0 : (blockIdx.y == 1 ? W1 : W2);
    int i = blockIdx.x * 256 + threadIdx.x;
    int d = i >> 7, c = i & 127;
    WT[(size_t)blockIdx.y * kH * kH + c * kH + d] = bf16bits(W[d * kH + c]);
}

// ---------------- linear (bf16 MFMA) + row-norm + transpose-out ----------------
__global__ __launch_bounds__(256) void linear_tr_kernel(
    const ushort* __restrict__ h16, const ushort* __restrict__ WT,
    const float* __restrict__ bias, ushort* __restrict__ t16,
    ushort* __restrict__ tT16, float* __restrict__ invn)
{
    __shared__ float ssb[64][2];
    __shared__ ushort tr[128 * 72];

    const int tid = threadIdx.x, lane = tid & 63, wid = tid >> 6;
    const int wr = wid >> 1, wc = wid & 1, quad = lane >> 4, l16 = lane & 15;
    const int rowbase = blockIdx.x * 64;
    const int b = rowbase / kN, q0 = rowbase % kN;

    f32x4 acc[2][4];
#pragma unroll
    for (int i = 0; i < 2; ++i)
#pragma unroll
        for (int ct = 0; ct < 4; ++ct) acc[i][ct] = (f32x4){0.f, 0.f, 0.f, 0.f};

#pragma unroll
    for (int k = 0; k < 4; ++k) {
        bf16x8 Af[2], Bf[4];
#pragma unroll
        for (int i = 0; i < 2; ++i)
            Af[i] = *(const bf16x8*)&h16[(size_t)(rowbase + wr * 32 + i * 16 + l16) * kH + k * 32 + quad * 8];
#pragma unroll
        for (int ct = 0; ct < 4; ++ct)
            Bf[ct] = *(const bf16x8*)&WT[(size_t)(wc * 64 + ct * 16 + l16) * kH + k * 32 + quad * 8];
#pragma unroll
        for (int i = 0; i < 2; ++i)
#pragma unroll
            for (int ct = 0; ct < 4; ++ct)
                acc[i][ct] = __builtin_amdgcn_mfma_f32_16x16x32_bf16(Af[i], Bf[ct], acc[i][ct], 0, 0, 0);
    }

    float bsr[4];
#pragma unroll
    for (int ct = 0; ct < 4; ++ct) bsr[ct] = bias[wc * 64 + ct * 16 + l16];

    f32x4 ss[2] = {(f32x4){0,0,0,0}, (f32x4){0,0,0,0}};
#pragma unroll
    for (int i = 0; i < 2; ++i)
#pragma unroll
        for (int ct = 0; ct < 4; ++ct)
#pragma unroll
            for (int r = 0; r < 4; ++r) {
                float v = acc[i][ct][r] + bsr[ct];
                acc[i][ct][r] = v;
                ss[i][r] += v * v;
            }
#pragma unroll
    for (int step = 1; step < 16; step <<= 1)
#pragma unroll
        for (int i = 0; i < 2; ++i)
#pragma unroll
            for (int r = 0; r < 4; ++r) ss[i][r] += __shfl_xor(ss[i][r], step);

    if (l16 == 0)
#pragma unroll
        for (int i = 0; i < 2; ++i)
#pragma unroll
            for (int r = 0; r < 4; ++r)
                ssb[wr * 32 + i * 16 + quad * 4 + r][wc] = ss[i][r];
    __syncthreads();
    if (tid < 64) {
        float s2 = ssb[tid][0] + ssb[tid][1];
        invn[rowbase + tid] = 1.f / fmaxf(sqrtf(s2), 1e-12f);
    }

#pragma unroll
    for (int i = 0; i < 2; ++i)
#pragma unroll
        for (int ct = 0; ct < 4; ++ct)
#pragma unroll
            for (int r = 0; r < 4; ++r) {
                const int pl = wr * 32 + i * 16 + quad * 4 + r;
                const int c = wc * 64 + ct * 16 + l16;
                ushort bits = bf16bits(acc[i][ct][r]);
                t16[(size_t)(rowbase + pl) * kH + c] = bits;
                tr[c * 72 + pl] = bits;
            }
    __syncthreads();

    ushort* tTb = tT16 + (size_t)b * kH * kN;
#pragma unroll
    for (int it = 0; it < 4; ++it) {
        int idx = tid + 256 * it;
        int c = idx >> 3, ch = idx & 7;
        bf16x8 v = *(const bf16x8*)&tr[c * 72 + ch * 8];
        *(bf16x8*)&tTb[(size_t)c * kN + q0 + ch * 8] = v;
    }
}

// ---------------- fused MFMA aggregation ----------------
// 512 blocks (2/CU), 256 thr = 4 waves. P-tile 32, q-tile 64.
// S-phase waves: wsp(2, p-16) x wsq(2, q-32). O-phase: wop(2, p-16) x woc(2, c-64).
__global__ __launch_bounds__(256, 2) void agg_kernel(
    const ushort* __restrict__ t, const ushort* __restrict__ tT,
    const float* __restrict__ invn, const ushort* __restrict__ ew16,
    ushort* __restrict__ hout, float* __restrict__ fout, int last)
{
    __shared__ ushort TQ[64 * 136];   // [q][d]  17408 B
    __shared__ ushort TT[128 * 72];   // [c][q]  18432 B
    __shared__ ushort Spm[32 * 72];   //  4608 B
    __shared__ float invPs[32];

    const int b = blockIdx.y, pbase = blockIdx.x * 32;
    const int tid = threadIdx.x, lane = tid & 63, wid = tid >> 6;
    const int quad = lane >> 4, l16 = lane & 15;
    const int wsp = wid >> 1, wsq = wid & 1;
    const int wop = wid >> 1, woc = wid & 1;

    const ushort* tb  = t  + (size_t)b * kN * kH;
    const ushort* tTb = tT + (size_t)b * kH * kN;
    const ushort* ewb = ew16 + (size_t)b * kN * kN;
    const float*  invb = invn + b * kN;

    if (tid < 32) invPs[tid] = invb[pbase + tid];

    // persistent S-phase A-frags (m=16 rows per wave-p-half)
    bf16x8 Af[4];
#pragma unroll
    for (int k = 0; k < 4; ++k)
        Af[k] = *(const bf16x8*)&tb[(size_t)(pbase + wsp * 16 + l16) * kH + k * 32 + quad * 8];

    // staging maps (coalesced): TQ 64rows x 256B (4 thr/row); TT 128rows x 128B (8 thr/row)
    const int qrow = tid >> 2, qcol = (tid & 3) * 8;   // + j*32
    const int trow = tid >> 3, tcol = (tid & 7) * 8;   // rows + j*32

    bf16x8 rQ[4], rT[4];
#pragma unroll
    for (int j = 0; j < 4; ++j) {
        rQ[j] = *(const bf16x8*)&tb[(size_t)qrow * kH + qcol + j * 32];
        rT[j] = *(const bf16x8*)&tTb[(size_t)(trow + j * 32) * kN + tcol];
    }

    const int ewRow = pbase + wsp * 16 + quad * 4;
    ushort ewc[2][4], ewn[2][4];
    float invQc[2], invQn[2];
#pragma unroll
    for (int jt = 0; jt < 2; ++jt) {
        const int qc = wsq * 32 + jt * 16 + l16;
        invQc[jt] = invb[qc];
#pragma unroll
        for (int r = 0; r < 4; ++r) ewc[jt][r] = ewb[(size_t)(ewRow + r) * kN + qc];
    }

    f32x4 oacc[4];
#pragma unroll
    for (int ct = 0; ct < 4; ++ct) oacc[ct] = (f32x4){0.f, 0.f, 0.f, 0.f};

    __syncthreads();

    for (int qt = 0; qt < kN / 64; ++qt) {
        const int qbase = qt * 64;

        // publish staged tile
#pragma unroll
        for (int j = 0; j < 4; ++j) {
            *(bf16x8*)&TQ[qrow * 136 + qcol + j * 32] = rQ[j];
            *(bf16x8*)&TT[(trow + j * 32) * 72 + tcol] = rT[j];
        }
        __syncthreads();

        // prefetch next tile (stays in flight through S-phase)
        if (qt + 1 < kN / 64) {
            const int qb2 = qbase + 64;
#pragma unroll
            for (int j = 0; j < 4; ++j) {
                rQ[j] = *(const bf16x8*)&tb[(size_t)(qb2 + qrow) * kH + qcol + j * 32];
                rT[j] = *(const bf16x8*)&tTb[(size_t)(trow + j * 32) * kN + qb2 + tcol];
            }
#pragma unroll
            for (int jt = 0; jt < 2; ++jt) {
                const int qc = qb2 + wsq * 32 + jt * 16 + l16;
                invQn[jt] = invb[qc];
#pragma unroll
                for (int r = 0; r < 4; ++r) ewn[jt][r] = ewb[(size_t)(ewRow + r) * kN + qc];
            }
        }

        // ---- S-phase: dacc[jt] = tP(16, wsp) . tQ(16, wsq*32+jt*16)^T ----
        f32x4 dacc[2] = {(f32x4){0,0,0,0}, (f32x4){0,0,0,0}};
#pragma unroll
        for (int k = 0; k < 4; ++k) {
            bf16x8 Bf0 = *(const bf16x8*)&TQ[(wsq * 32 + l16) * 136 + k * 32 + quad * 8];
            bf16x8 Bf1 = *(const bf16x8*)&TQ[(wsq * 32 + 16 + l16) * 136 + k * 32 + quad * 8];
            dacc[0] = __builtin_amdgcn_mfma_f32_16x16x32_bf16(Af[k], Bf0, dacc[0], 0, 0, 0);
            dacc[1] = __builtin_amdgcn_mfma_f32_16x16x32_bf16(Af[k], Bf1, dacc[1], 0, 0, 0);
        }
        // S' = dacc * ew * invQ -> bf16 -> Spm
#pragma unroll
        for (int jt = 0; jt < 2; ++jt)
#pragma unroll
            for (int r = 0; r < 4; ++r)
                Spm[(wsp * 16 + quad * 4 + r) * 72 + wsq * 32 + jt * 16 + l16] =
                    bf16bits(dacc[jt][r] * f16val(ewc[jt][r]) * invQc[jt]);
        __syncthreads();

        // ---- O-phase: oacc += S'[16p x 64q] @ t[64q x 64c] ----
#pragma unroll
        for (int k2 = 0; k2 < 2; ++k2) {
            bf16x8 Sa = *(const bf16x8*)&Spm[(wop * 16 + l16) * 72 + k2 * 32 + quad * 8];
#pragma unroll
            for (int ct = 0; ct < 4; ++ct) {
                bf16x8 Bb = *(const bf16x8*)&TT[(woc * 64 + ct * 16 + l16) * 72 + k2 * 32 + quad * 8];
                oacc[ct] = __builtin_amdgcn_mfma_f32_16x16x32_bf16(Sa, Bb, oacc[ct], 0, 0, 0);
            }
        }
        __syncthreads();

#pragma unroll
        for (int jt = 0; jt < 2; ++jt) {
            invQc[jt] = invQn[jt];
#pragma unroll
            for (int r = 0; r < 4; ++r) ewc[jt][r] = ewn[jt][r];
        }
    }

    // ---- store: O * invP (+relu -> bf16 h, or fp32 final) ----
#pragma unroll
    for (int ct = 0; ct < 4; ++ct)
#pragma unroll
        for (int r = 0; r < 4; ++r) {
            const int pl = wop * 16 + quad * 4 + r;
            const int p = pbase + pl;
            const int c = woc * 64 + ct * 16 + l16;
            float v = oacc[ct][r] * invPs[pl];
            if (!last) {
                hout[(size_t)b * kN * kH + (size_t)p * kH + c] = bf16bits(fmaxf(v, 0.f));
            } else {
                fout[(size_t)b * kN * kH + (size_t)p * kH + c] = v;
            }
        }
}

extern "C" void kernel_launch(void* const* d_in, const int* in_sizes, int n_in,
                              void* d_out, int out_size, void* d_ws, size_t ws_size,
                              hipStream_t stream) {
    const float* x  = (const float*)d_in[0];
    const float* ew = (const float*)d_in[1];
    const float* W0 = (const float*)d_in[2];
    const float* b0 = (const float*)d_in[3];
    const float* W1 = (const float*)d_in[4];
    const float* b1 = (const float*)d_in[5];
    const float* W2 = (const float*)d_in[6];
    const float* b2 = (const float*)d_in[7];
    const float* bias[3] = {b0, b1, b2};

    const size_t nBNH = (size_t)kB * kN * kH;          // 2M
    const size_t nBNN = (size_t)kB * kN * kN;          // 33.55M
    ushort* h16  = (ushort*)d_ws;                      // [B,N,H]
    ushort* t16  = h16 + nBNH;                         // [B,N,H]
    ushort* tT16 = t16 + nBNH;                         // [B,H,N]
    float*  invn = (float*)(tT16 + nBNH);              // [B,N]
    ushort* WT   = (ushort*)(invn + (size_t)kB * kN);  // 3 x [H,D]
    ushort* ew16 = WT + (size_t)3 * kH * kH;           // [B,N,N] fp16, 67 MB
    float*  out  = (float*)d_out;

    cvt_ew_kernel<<<(int)(nBNN / 4 / 256), 256, 0, stream>>>(ew, ew16);
    cvt_bf16_kernel<<<(int)(nBNH / 4 + 255) / 256, 256, 0, stream>>>(x, h16, (int)(nBNH / 4));
    cvt_wT_kernel<<<dim3(64, 3), 256, 0, stream>>>(W0, W1, W2, WT);

    for (int layer = 0; layer < 3; ++layer) {
        linear_tr_kernel<<<kB * kN / 64, 256, 0, stream>>>(
            h16, WT + (size_t)layer * kH * kH, bias[layer], t16, tT16, invn);
        agg_kernel<<<dim3(kN / 32, kB), 256, 0, stream>>>(
            t16, tT16, invn, ew16, h16, out, layer == 2 ? 1 : 0);
    }
}